// Round 10
// baseline (754.825 us; speedup 1.0000x reference)
//
#include <hip/hip_runtime.h>
#include <hip/hip_bf16.h>
#include <stdint.h>

// Problem constants (fixed by setup_inputs)
#define E_ 8
#define C_ 2048
#define H_ 2048
#define I_ 2816
#define N1_ (2 * I_)   // 5632

typedef __attribute__((ext_vector_type(8))) short bf16x8;
typedef __attribute__((ext_vector_type(4))) float f32x4;

__device__ __forceinline__ unsigned short f2bf(float f) {
  union { float f; unsigned int u; } v; v.f = f;
  unsigned int u = v.u;
  unsigned int r = (u + 0x7FFFu + ((u >> 16) & 1u)) >> 16;  // RNE
  return (unsigned short)r;
}

__device__ __forceinline__ void gload16(const unsigned short* g, char* l) {
  __builtin_amdgcn_global_load_lds(
      (const __attribute__((address_space(1))) unsigned int*)g,
      (__attribute__((address_space(3))) unsigned int*)l, 16, 0, 0);
}

#define BARX()  do { asm volatile("" ::: "memory"); __builtin_amdgcn_s_barrier(); asm volatile("" ::: "memory"); } while (0)
#define LGKM0() asm volatile("s_waitcnt lgkmcnt(0)" ::: "memory")
#define VMC(n)  asm volatile("s_waitcnt vmcnt(" #n ")" ::: "memory")
#define PRIO(p) __builtin_amdgcn_s_setprio(p)

// ---------------- fp32 -> bf16 straight conversion (vectorized 8/thread) ----
__global__ __launch_bounds__(256) void cvt_bf16(const float* __restrict__ src,
                                                unsigned short* __restrict__ dst,
                                                int n8) {
  int idx = blockIdx.x * 256 + threadIdx.x;
  int stride = gridDim.x * 256;
  for (int i = idx; i < n8; i += stride) {
    const float4* s = (const float4*)(src + (size_t)i * 8);
    float4 a = s[0], b = s[1];
    uint4 o;
    o.x = (unsigned int)f2bf(a.x) | ((unsigned int)f2bf(a.y) << 16);
    o.y = (unsigned int)f2bf(a.z) | ((unsigned int)f2bf(a.w) << 16);
    o.z = (unsigned int)f2bf(b.x) | ((unsigned int)f2bf(b.y) << 16);
    o.w = (unsigned int)f2bf(b.z) | ((unsigned int)f2bf(b.w) << 16);
    *(uint4*)(dst + (size_t)i * 8) = o;
  }
}

// ------- fp32 [R][C] -> bf16 [C][R] per-expert transpose, 64c x 256r tiles --
__global__ __launch_bounds__(256) void transpose_cvt(const float* __restrict__ src,
                                                     unsigned short* __restrict__ dst,
                                                     int R, int C) {
  int tilesC = C >> 6, tilesR = R >> 8;
  int tiles = tilesR * tilesC;
  int bid = blockIdx.x;
  int e = bid / tiles;
  int r2 = bid % tiles;
  int tr = r2 / tilesC, tc = r2 % tilesC;
  const float* s = src + (size_t)e * R * C + (size_t)(tr << 8) * C + (tc << 6);
  unsigned short* d = dst + (size_t)e * R * C + (size_t)(tc << 6) * R + (tr << 8);

  __shared__ unsigned short lds[64 * 256];
  int t = threadIdx.x;
  int tx = t & 15, ty = t >> 4;
  const int g = tx & 7;
#pragma unroll
  for (int p = 0; p < 16; ++p) {
    int row = p * 16 + ty;
    float4 v = *(const float4*)(s + (size_t)row * C + tx * 4);
    int base = tx * 1024 + (((row >> 3) ^ g) << 3) + (row & 7);  // col=4tx
    lds[base]       = f2bf(v.x);
    lds[base + 256] = f2bf(v.y);
    lds[base + 512] = f2bf(v.z);
    lds[base + 768] = f2bf(v.w);
  }
  __syncthreads();
#pragma unroll
  for (int it = 0; it < 8; ++it) {
    int q = it * 256 + t;
    int c = q >> 5, l = q & 31;
    int a = c * 256 + ((l ^ ((c >> 2) & 7)) << 3);
    uint4 vv = *(const uint4*)(&lds[a]);
    *(uint4*)(d + (size_t)c * R + l * 8) = vv;
  }
}

// Embedded down-transpose: 2 tiles (256r x 64c) per gemm1 block (32KB LDS).
__device__ __forceinline__ void down_trans2(const float* __restrict__ down,
                                            unsigned short* __restrict__ downT,
                                            char* ldsbuf, int bid, int t) {
  unsigned short* tl = (unsigned short*)ldsbuf;
  const int tx = t & 15, ty = t >> 4;            // ty 0..31
  const int gx = tx & 7;
#pragma unroll 1
  for (int sub = 0; sub < 2; ++sub) {
    const int T = bid * 2 + sub;                 // 0..2815
    const int te = T / 352;
    const int rr = T % 352;
    const int tr = rr >> 5, tc = rr & 31;
    const float* s = down + (size_t)te * I_ * H_ + (size_t)(tr << 8) * H_ + (tc << 6);
    unsigned short* d = downT + (size_t)te * I_ * H_ + (size_t)(tc << 6) * I_ + (tr << 8);
    __syncthreads();
#pragma unroll
    for (int p = 0; p < 8; ++p) {
      int row = p * 32 + ty;
      float4 v = *(const float4*)(s + (size_t)row * H_ + tx * 4);
      int base = tx * 1024 + (((row >> 3) ^ gx) << 3) + (row & 7);
      tl[base]       = f2bf(v.x);
      tl[base + 256] = f2bf(v.y);
      tl[base + 512] = f2bf(v.z);
      tl[base + 768] = f2bf(v.w);
    }
    __syncthreads();
#pragma unroll
    for (int it = 0; it < 4; ++it) {
      int q = it * 512 + t;
      int c = q >> 5, l = q & 31;
      int a = c * 256 + ((l ^ ((c >> 2) & 7)) << 3);
      uint4 vv = *(const uint4*)(&tl[a]);
      *(uint4*)(d + (size_t)c * I_ + l * 8) = vv;
    }
  }
  __syncthreads();
}

// ====== GEMM1: 256x128 dual-B, BK=32, A-dbuf + B-tribuf = 80KB LDS ==========
// 2 blocks/CU (vs 1 at 128KB): partner block hides barrier stalls + transpose.
// Per K-tile(32): 2 phases (gate, up), 16 MFMA + 2 barriers each; VMC(4) ledger.
// LDS swizzle: [row][chunk], chunk(row,kb) = kb ^ (row&3) ^ ((row>>2)&3).
__global__ __launch_bounds__(512, 2) void gemm1_glu(const unsigned short* __restrict__ A,
                                                    const unsigned short* __restrict__ BT,
                                                    unsigned short* __restrict__ act,
                                                    const float* __restrict__ down,
                                                    unsigned short* __restrict__ downT) {
  constexpr int MT = C_ / 256;   // 8
  constexpr int NT = I_ / 128;   // 22
  constexpr int NK2 = H_ / 32;   // 64 K-tiles
  const int nwg = E_ * MT * NT;  // 1408
  int bid = blockIdx.x;
  int swz = (bid & 7) * (nwg >> 3) + (bid >> 3);
  int e = swz / (MT * NT);
  int r2 = swz % (MT * NT);
  int m0 = (r2 % MT) << 8;
  int n0 = (r2 / MT) << 7;

  const unsigned short* Ae = A + (size_t)e * C_ * H_ + (size_t)m0 * H_;
  const unsigned short* Ge = BT + (size_t)e * N1_ * H_ + (size_t)n0 * H_;
  const unsigned short* Ue = Ge + (size_t)I_ * H_;
  unsigned short* Ce = act + (size_t)e * C_ * I_;

  __shared__ char lds[81920];   // A: 2x16KB, B: 3x16KB

  const int t = threadIdx.x, lane = t & 63, w = t >> 6;
  const int wr = (w >> 2) << 7;   // 0 / 128
  const int wc = (w & 3) << 5;    // 0,32,64,96

  const int la = lane & 15, kb = lane >> 4;  // kb = k-chunk 0..3
  const int ar = wr + la;
  const int br = wc + la;

  // even blocks: down-transpose first (partner block computes meanwhile)
  if ((bid & 1) == 0) down_trans2(down, downT, lds, bid, t);

  char* a0c = lds;
  char* a1c = lds + 16384;
  char* b0c = lds + 32768;
  char* b1c = lds + 49152;
  char* b2c = lds + 65536;

  // staging source pre-swizzle: thread -> row sr = t>>2 (x2 calls), chunk sc = t&3
  const int sr = t >> 2, sc = t & 3;
  const int scs = sc ^ (sr & 3) ^ ((sr >> 2) & 3);  // inverse-swizzled k-chunk
  const int sofA = sr * H_ + (scs << 3);            // elements
  const int t16 = t << 4;

#define STGA1(ko, dst) do { \
    gload16(Ae + (ko) + sofA,            (dst) + t16); \
    gload16(Ae + (ko) + sofA + 128 * H_, (dst) + t16 + 8192); } while (0)
#define STGB1(ko, dst) do { \
    gload16(Ge + (ko) + sofA, (dst) + t16); \
    gload16(Ue + (ko) + sofA, (dst) + t16 + 8192); } while (0)

  // frag reads: row*64 + chunk(row)*16
#define CHB(row) (((kb ^ ((row) & 3) ^ (((row) >> 2) & 3))) << 4)
#define RDA1(buf) \
  _Pragma("unroll") for (int mi = 0; mi < 8; ++mi) { \
    const int rw = ar + mi * 16; \
    fa[mi] = *(const bf16x8*)((buf) + rw * 64 + CHB(rw)); }
#define RDB1(buf, dst, ro) \
  _Pragma("unroll") for (int ni = 0; ni < 2; ++ni) { \
    const int rw = br + ni * 16; \
    dst[ni] = *(const bf16x8*)((buf) + ((ro) + rw) * 64 + CHB(rw)); }
#define MMG1(accA, bfr) \
  _Pragma("unroll") for (int mi = 0; mi < 8; ++mi) \
  _Pragma("unroll") for (int ni = 0; ni < 2; ++ni) \
    accA[mi][ni] = __builtin_amdgcn_mfma_f32_16x16x32_bf16(fa[mi], bfr[ni], accA[mi][ni], 0, 0, 0);

  f32x4 accg[8][2] = {};
  f32x4 accu[8][2] = {};
  bf16x8 fa[8], fg[2], fu[2];

  // prologue: A(0),B(0) first (oldest), then A(1),B(1); wait oldest 4
  STGA1(0, a0c); STGB1(0, b0c);
  STGA1(32, a1c); STGB1(32, b1c);
  VMC(4); BARX();

#pragma unroll 1
  for (int tt = 0; tt < NK2; ++tt) {
    const int ko = (tt + 2) * 32;
    const bool nx = (tt + 2 < NK2);
    // P1 (gate): read A(tt) all 8 frags + B(tt) gate; stage B(tt+2) -> b2
    RDA1(a0c); RDB1(b0c, fg, 0);
    if (nx) STGB1(ko, b2c);
    BARX(); LGKM0();
    PRIO(1); MMG1(accg, fg); PRIO(0); BARX();
    // P2 (up): read B(tt) up; stage A(tt+2) -> a0 (just fully read)
    RDB1(b0c, fu, 128);
    if (nx) STGA1(ko, a0c);
    BARX(); LGKM0();
    PRIO(1); MMG1(accu, fu); PRIO(0);
    if (tt < NK2 - 2) { VMC(4); } else { VMC(0); }
    BARX();
    // rotate buffers
    char* ta = a0c; a0c = a1c; a1c = ta;
    char* tb = b0c; b0c = b1c; b1c = b2c; b2c = tb;
  }

  // Epilogue: act = silu(g) * u. C/D layout: col=lane&15, row=(lane>>4)*4+reg
  const int rb = m0 + wr + (kb << 2);
  const int cb = n0 + wc + la;
#pragma unroll
  for (int mi = 0; mi < 8; ++mi)
#pragma unroll
    for (int ni = 0; ni < 2; ++ni)
#pragma unroll
      for (int r = 0; r < 4; ++r) {
        float g = accg[mi][ni][r], u = accu[mi][ni][r];
        float s = g / (1.0f + __expf(-g));
        Ce[(size_t)(rb + mi * 16 + r) * I_ + (cb + ni * 16)] = f2bf(s * u);
      }

  // odd blocks: down-transpose last
  if (bid & 1) down_trans2(down, downT, lds, bid, t);
}

// Shared frag-read macro for gemm2: tiles linear [rows][128B], XOR2 swizzle.
#define RDA(buf, m4) \
  _Pragma("unroll") for (int mi = 0; mi < 4; ++mi) \
  _Pragma("unroll") for (int kk = 0; kk < 2; ++kk) \
    fa[(m4) + mi][kk] = *(const bf16x8*)((buf) + (ar + ((m4) + mi) * 16) * 128 + ((((kk << 2) | kb) ^ s7a) << 4));

// ===================== GEMM2: 256x256 8-phase, fp32 out =====================
__global__ __launch_bounds__(512, 2) void gemm2_down(const unsigned short* __restrict__ A,
                                                     const unsigned short* __restrict__ BT,
                                                     float* __restrict__ Out) {
  constexpr int MT = C_ / 256;   // 8
  constexpr int NT = H_ / 256;   // 8
  constexpr int NK = I_ / 64;    // 44
  constexpr int NIT = NK / 2;    // 22
  const int nwg = E_ * MT * NT;  // 512
  int bid = blockIdx.x;
  int swz = (bid & 7) * (nwg >> 3) + (bid >> 3);
  int e = swz / (MT * NT);
  int r2 = swz % (MT * NT);
  int m0 = (r2 % MT) << 8;
  int n0 = (r2 / MT) << 8;

  const unsigned short* Ae = A + (size_t)e * C_ * I_ + (size_t)m0 * I_;
  const unsigned short* Be = BT + (size_t)e * H_ * I_ + (size_t)n0 * I_;
  float* Oe = Out + (size_t)e * C_ * H_;

  __shared__ char lds[131072];
  char* const A0b = lds;
  char* const A1b = lds + 32768;
  char* const B0b = lds + 65536;
  char* const B1b = lds + 98304;

  const int t = threadIdx.x, lane = t & 63, w = t >> 6;
  const int wr = (w >> 2) << 7;   // 0 / 128
  const int wc = (w & 3) << 6;    // 0,64,128,192

  const int la = lane & 15, kb = lane >> 4;
  const int ar = wr + la, s7a = ar & 7;
  const int br = wc + la, s7b = br & 7;

  const int sr0 = t >> 3, sc0 = t & 7;
  const int sof0 = sr0 * I_ + ((sc0 ^ (sr0 & 7)) << 3);
  const int sof1 = sof0 + 64 * I_;
  const int dof0 = t << 4, dof1 = (t << 4) + 8192;

#define STG2(gb, ko, lb) do { \
    gload16((gb) + (ko) + sof0, (lb) + dof0); \
    gload16((gb) + (ko) + sof1, (lb) + dof1); } while (0)

#define RDB2(buf, n2) \
  _Pragma("unroll") for (int ni = 0; ni < 2; ++ni) \
  _Pragma("unroll") for (int kk = 0; kk < 2; ++kk) \
    fb[(n2) + ni][kk] = *(const bf16x8*)((buf) + (br + ((n2) + ni) * 16) * 128 + ((((kk << 2) | kb) ^ s7b) << 4));

#define MM4(m4, n2) \
  _Pragma("unroll") for (int mi = 0; mi < 4; ++mi) \
  _Pragma("unroll") for (int ni = 0; ni < 2; ++ni) \
  _Pragma("unroll") for (int kk = 0; kk < 2; ++kk) \
    acc[(m4) + mi][(n2) + ni] = __builtin_amdgcn_mfma_f32_16x16x32_bf16(fa[(m4) + mi][kk], fb[(n2) + ni][kk], acc[(m4) + mi][(n2) + ni], 0, 0, 0);

  f32x4 acc[8][4] = {};
  bf16x8 fa[8][2], fb[4][2];

  // prologue
  STG2(Ae, 0, A0b); STG2(Ae + 128 * I_, 0, A0b + 16384);
  STG2(Be, 0, B0b); STG2(Be + 128 * I_, 0, B0b + 16384);
  STG2(Ae, 64, A1b); STG2(Ae + 128 * I_, 64, A1b + 16384);
  VMC(4); BARX();

#pragma unroll 1
  for (int i = 0; i < NIT; ++i) {
    const int kc = i * 128;
    const bool nx = (i + 1 < NIT);
    // ph1
    RDA(A0b, 0); RDB2(B0b, 0);
    STG2(Be, kc + 64, B1b);
    BARX(); LGKM0();
    PRIO(1); MM4(0, 0); PRIO(0); BARX();
    // ph2
    RDB2(B0b, 2);
    STG2(Be + 128 * I_, kc + 64, B1b + 16384);
    BARX(); LGKM0();
    PRIO(1); MM4(0, 2); PRIO(0); BARX();
    // ph3
    RDA(A0b, 4);
    BARX(); LGKM0();
    PRIO(1); MM4(4, 0); PRIO(0); BARX();
    // ph4
    if (nx) { STG2(Ae, kc + 128, A0b); STG2(Ae + 128 * I_, kc + 128, A0b + 16384); VMC(4); }
    else VMC(0);
    BARX();
    PRIO(1); MM4(4, 2); PRIO(0); BARX();
    // ph5
    RDA(A1b, 0); RDB2(B1b, 0);
    if (nx) STG2(Be, kc + 128, B0b);
    BARX(); LGKM0();
    PRIO(1); MM4(0, 0); PRIO(0); BARX();
    // ph6
    RDB2(B1b, 2);
    if (nx) STG2(Be + 128 * I_, kc + 128, B0b + 16384);
    BARX(); LGKM0();
    PRIO(1); MM4(0, 2); PRIO(0); BARX();
    // ph7
    RDA(A1b, 4);
    BARX(); LGKM0();
    PRIO(1); MM4(4, 0); PRIO(0); BARX();
    // ph8
    if (nx) { STG2(Ae, kc + 192, A1b); STG2(Ae + 128 * I_, kc + 192, A1b + 16384); VMC(4); }
    BARX();
    PRIO(1); MM4(4, 2); PRIO(0); BARX();
  }

  const int rb = m0 + wr + (kb << 2);
  const int cb = n0 + wc + la;
#pragma unroll
  for (int mi = 0; mi < 8; ++mi)
#pragma unroll
    for (int ni = 0; ni < 4; ++ni)
#pragma unroll
      for (int r = 0; r < 4; ++r)
        Oe[(size_t)(rb + mi * 16 + r) * H_ + (cb + ni * 16)] = acc[mi][ni][r];
#undef STG2
}

extern "C" void kernel_launch(void* const* d_in, const int* in_sizes, int n_in,
                              void* d_out, int out_size, void* d_ws, size_t ws_size,
                              hipStream_t stream) {
  const float* hidden = (const float*)d_in[0];
  const float* gateup = (const float*)d_in[1];
  const float* down = (const float*)d_in[2];
  float* out = (float*)d_out;

  unsigned short* ws = (unsigned short*)d_ws;
  unsigned short* hiddenB = ws;                                   // E*C*H bf16
  unsigned short* gateupT = hiddenB + (size_t)E_ * C_ * H_;       // E*2I*H bf16 (transposed)
  unsigned short* downT = gateupT + (size_t)E_ * N1_ * H_;        // E*H*I bf16 (transposed)
  unsigned short* actB = downT + (size_t)E_ * I_ * H_;            // E*C*I bf16

  cvt_bf16<<<2048, 256, 0, stream>>>(hidden, hiddenB, (E_ * C_ * H_) / 8);
  transpose_cvt<<<E_ * (H_ / 256) * (N1_ / 64), 256, 0, stream>>>(gateup, gateupT, H_, N1_);
  gemm1_glu<<<E_ * (C_ / 256) * (I_ / 128), 512, 0, stream>>>(hiddenB, gateupT, actB, down, downT);
  gemm2_down<<<E_ * (C_ / 256) * (H_ / 256), 512, 0, stream>>>(actB, downT, out);
}

// Round 11
// 752.019 us; speedup vs baseline: 1.0037x; 1.0037x over previous
//
#include <hip/hip_runtime.h>
#include <hip/hip_bf16.h>
#include <stdint.h>

// Problem constants (fixed by setup_inputs)
#define E_ 8
#define C_ 2048
#define H_ 2048
#define I_ 2816
#define N1_ (2 * I_)   // 5632

typedef __attribute__((ext_vector_type(8))) short bf16x8;
typedef __attribute__((ext_vector_type(4))) float f32x4;

__device__ __forceinline__ unsigned short f2bf(float f) {
  union { float f; unsigned int u; } v; v.f = f;
  unsigned int u = v.u;
  unsigned int r = (u + 0x7FFFu + ((u >> 16) & 1u)) >> 16;  // RNE
  return (unsigned short)r;
}

__device__ __forceinline__ void gload16(const unsigned short* g, char* l) {
  __builtin_amdgcn_global_load_lds(
      (const __attribute__((address_space(1))) unsigned int*)g,
      (__attribute__((address_space(3))) unsigned int*)l, 16, 0, 0);
}

#define BARX()  do { asm volatile("" ::: "memory"); __builtin_amdgcn_s_barrier(); asm volatile("" ::: "memory"); } while (0)
#define LGKM0() asm volatile("s_waitcnt lgkmcnt(0)" ::: "memory")
#define VMC(n)  asm volatile("s_waitcnt vmcnt(" #n ")" ::: "memory")
#define PRIO(p) __builtin_amdgcn_s_setprio(p)

// ---------------- fp32 -> bf16 straight conversion (vectorized 8/thread) ----
__global__ __launch_bounds__(256) void cvt_bf16(const float* __restrict__ src,
                                                unsigned short* __restrict__ dst,
                                                int n8) {
  int idx = blockIdx.x * 256 + threadIdx.x;
  int stride = gridDim.x * 256;
  for (int i = idx; i < n8; i += stride) {
    const float4* s = (const float4*)(src + (size_t)i * 8);
    float4 a = s[0], b = s[1];
    uint4 o;
    o.x = (unsigned int)f2bf(a.x) | ((unsigned int)f2bf(a.y) << 16);
    o.y = (unsigned int)f2bf(a.z) | ((unsigned int)f2bf(a.w) << 16);
    o.z = (unsigned int)f2bf(b.x) | ((unsigned int)f2bf(b.y) << 16);
    o.w = (unsigned int)f2bf(b.z) | ((unsigned int)f2bf(b.w) << 16);
    *(uint4*)(dst + (size_t)i * 8) = o;
  }
}

// ------- fp32 [R][C] -> bf16 [C][R] per-expert transpose, 64c x 256r tiles --
__global__ __launch_bounds__(256) void transpose_cvt(const float* __restrict__ src,
                                                     unsigned short* __restrict__ dst,
                                                     int R, int C) {
  int tilesC = C >> 6, tilesR = R >> 8;
  int tiles = tilesR * tilesC;
  int bid = blockIdx.x;
  int e = bid / tiles;
  int r2 = bid % tiles;
  int tr = r2 / tilesC, tc = r2 % tilesC;
  const float* s = src + (size_t)e * R * C + (size_t)(tr << 8) * C + (tc << 6);
  unsigned short* d = dst + (size_t)e * R * C + (size_t)(tc << 6) * R + (tr << 8);

  __shared__ unsigned short lds[64 * 256];
  int t = threadIdx.x;
  int tx = t & 15, ty = t >> 4;
  const int g = tx & 7;
#pragma unroll
  for (int p = 0; p < 16; ++p) {
    int row = p * 16 + ty;
    float4 v = *(const float4*)(s + (size_t)row * C + tx * 4);
    int base = tx * 1024 + (((row >> 3) ^ g) << 3) + (row & 7);  // col=4tx
    lds[base]       = f2bf(v.x);
    lds[base + 256] = f2bf(v.y);
    lds[base + 512] = f2bf(v.z);
    lds[base + 768] = f2bf(v.w);
  }
  __syncthreads();
#pragma unroll
  for (int it = 0; it < 8; ++it) {
    int q = it * 256 + t;
    int c = q >> 5, l = q & 31;
    int a = c * 256 + ((l ^ ((c >> 2) & 7)) << 3);
    uint4 vv = *(const uint4*)(&lds[a]);
    *(uint4*)(d + (size_t)c * R + l * 8) = vv;
  }
}

// Embedded down-transpose: ONE 256r x 64c tile per gemm1 block (32KB LDS).
__device__ __forceinline__ void down_trans1(const float* __restrict__ down,
                                            unsigned short* __restrict__ downT,
                                            char* ldsbuf, int T, int t) {
  unsigned short* tl = (unsigned short*)ldsbuf;
  const int tx = t & 15, ty = t >> 4;            // ty 0..31 (512 threads)
  const int gx = tx & 7;
  const int te = T / 352;                        // tiles/expert = 11*32
  const int rr = T % 352;
  const int tr = rr >> 5, tc = rr & 31;
  const float* s = down + (size_t)te * I_ * H_ + (size_t)(tr << 8) * H_ + (tc << 6);
  unsigned short* d = downT + (size_t)te * I_ * H_ + (size_t)(tc << 6) * I_ + (tr << 8);
  __syncthreads();
#pragma unroll
  for (int p = 0; p < 8; ++p) {
    int row = p * 32 + ty;
    float4 v = *(const float4*)(s + (size_t)row * H_ + tx * 4);
    int base = tx * 1024 + (((row >> 3) ^ gx) << 3) + (row & 7);
    tl[base]       = f2bf(v.x);
    tl[base + 256] = f2bf(v.y);
    tl[base + 512] = f2bf(v.z);
    tl[base + 768] = f2bf(v.w);
  }
  __syncthreads();
#pragma unroll
  for (int it = 0; it < 4; ++it) {
    int q = it * 512 + t;
    int c = q >> 5, l = q & 31;
    int a = c * 256 + ((l ^ ((c >> 2) & 7)) << 3);
    uint4 vv = *(const uint4*)(&tl[a]);
    *(uint4*)(d + (size_t)c * I_ + l * 8) = vv;
  }
  __syncthreads();
}

// ====== GEMM1: 128x128 dual-B, BK=64, A-dbuf + B-tribuf (128KB) =============
// Grid 2816 = exactly 11 rounds of 256 CUs -> zero dispatch tail.
// Same proven pieces as the 256x128 kernel: 128B rows, XOR2 swizzle, STG
// pattern, 16 MFMA + 2 barriers per phase, VMC(6) with 2-3 phase lead.
__global__ __launch_bounds__(512, 2) void gemm1_glu(const unsigned short* __restrict__ A,
                                                    const unsigned short* __restrict__ BT,
                                                    unsigned short* __restrict__ act,
                                                    const float* __restrict__ down,
                                                    unsigned short* __restrict__ downT) {
  constexpr int MT = C_ / 128;   // 16
  constexpr int NT = I_ / 128;   // 22
  constexpr int NK = H_ / 64;    // 32 K-tiles
  const int nwg = E_ * MT * NT;  // 2816
  int bid = blockIdx.x;
  int swz = (bid & 7) * (nwg >> 3) + (bid >> 3);
  int e = swz / (MT * NT);
  int r2 = swz % (MT * NT);
  int m0 = (r2 % MT) << 7;
  int n0 = (r2 / MT) << 7;

  const unsigned short* Ae = A + (size_t)e * C_ * H_ + (size_t)m0 * H_;
  const unsigned short* Ge = BT + (size_t)e * N1_ * H_ + (size_t)n0 * H_;
  const unsigned short* Ue = Ge + (size_t)I_ * H_;
  unsigned short* Ce = act + (size_t)e * C_ * I_;

  __shared__ char lds[131072];

  const int t = threadIdx.x, lane = t & 63, w = t >> 6;
  const int wr = (w >> 2) << 6;   // 0 / 64   (2 M-waves)
  const int wc = (w & 3) << 5;    // 0,32,64,96 (4 N-waves)

  const int la = lane & 15, kb = lane >> 4;
  const int ar = wr + la, s7a = ar & 7;
  const int br = wc + la, s7b = br & 7;

  // even blocks: down-transpose first; odd: after (stagger BW vs compute)
  if ((bid & 1) == 0) down_trans1(down, downT, lds, bid, t);

  char* a0c = lds;            // A tiles 16KB x2
  char* a1c = lds + 16384;
  char* b0c = lds + 32768;    // B tiles 32KB x3 (gate @+0, up @+16384)
  char* b1c = lds + 65536;
  char* b2c = lds + 98304;

  const int sr0 = t >> 3, sc0 = t & 7;
  const int sofA = sr0 * H_ + ((sc0 ^ (sr0 & 7)) << 3);
  const int sofA1 = sofA + 64 * H_;
  const int dof0 = t << 4, dof1 = (t << 4) + 8192;

  // one STG = one 128x64 bf16 tile (16KB) via 2 gloads
#define STG1(gb, ko, lb) do { \
    gload16((gb) + (ko) + sofA,  (lb) + dof0); \
    gload16((gb) + (ko) + sofA1, (lb) + dof1); } while (0)

#define RDA1(buf) \
  _Pragma("unroll") for (int mi = 0; mi < 4; ++mi) \
  _Pragma("unroll") for (int kk = 0; kk < 2; ++kk) \
    fa[mi][kk] = *(const bf16x8*)((buf) + (ar + mi * 16) * 128 + ((((kk << 2) | kb) ^ s7a) << 4));

#define RDB1(buf, dst) \
  _Pragma("unroll") for (int ni = 0; ni < 2; ++ni) \
  _Pragma("unroll") for (int kk = 0; kk < 2; ++kk) \
    dst[ni][kk] = *(const bf16x8*)((buf) + (br + ni * 16) * 128 + ((((kk << 2) | kb) ^ s7b) << 4));

#define MMG1(accA, bfr) \
  _Pragma("unroll") for (int mi = 0; mi < 4; ++mi) \
  _Pragma("unroll") for (int ni = 0; ni < 2; ++ni) \
  _Pragma("unroll") for (int kk = 0; kk < 2; ++kk) \
    accA[mi][ni] = __builtin_amdgcn_mfma_f32_16x16x32_bf16(fa[mi][kk], bfr[ni][kk], accA[mi][ni], 0, 0, 0);

  f32x4 accg[4][2] = {};
  f32x4 accu[4][2] = {};
  bf16x8 fa[4][2], fg[2][2], fu[2][2];

  // prologue: tiles 0,1 -> {A0,B0},{A1,B1}; wait tile0's 6 (keep tile1's 6 in flight)
  STG1(Ae, 0, a0c);
  STG1(Ge, 0, b0c); STG1(Ue, 0, b0c + 16384);
  STG1(Ae, 64, a1c);
  STG1(Ge, 64, b1c); STG1(Ue, 64, b1c + 16384);
  VMC(6); BARX();

#pragma unroll 1
  for (int p = 0; p < NK; ++p) {
    const int ko = (p + 2) * 64;
    const bool nx = (p + 2 < NK);
    // ph_a (gate): read A(p)+Bg(p); stage Bg(p+2) -> b2
    RDA1(a0c); RDB1(b0c, fg);
    if (nx) STG1(Ge, ko, b2c);
    BARX(); LGKM0();
    PRIO(1); MMG1(accg, fg); PRIO(0); BARX();
    // ph_b (up): read Bu(p); stage Bu(p+2) -> b2, A(p+2) -> a0 (read done ph_a)
    RDB1(b0c + 16384, fu);
    if (nx) { STG1(Ue, ko, b2c + 16384); STG1(Ae, ko, a0c); }
    BARX(); LGKM0();
    PRIO(1); MMG1(accu, fu); PRIO(0);
    if (nx) { VMC(6); } else if (p == NK - 2) { VMC(0); }
    BARX();
    // rotate: A swap, B tri-rotate
    char* ta = a0c; a0c = a1c; a1c = ta;
    char* tb = b0c; b0c = b1c; b1c = b2c; b2c = tb;
  }

  // Epilogue: act = silu(g) * u. C/D layout: col=lane&15, row=(lane>>4)*4+reg
  const int rb = m0 + wr + (kb << 2);
  const int cb = n0 + wc + la;
#pragma unroll
  for (int mi = 0; mi < 4; ++mi)
#pragma unroll
    for (int ni = 0; ni < 2; ++ni)
#pragma unroll
      for (int r = 0; r < 4; ++r) {
        float g = accg[mi][ni][r], u = accu[mi][ni][r];
        float s = g / (1.0f + __expf(-g));
        Ce[(size_t)(rb + mi * 16 + r) * I_ + (cb + ni * 16)] = f2bf(s * u);
      }

  if (bid & 1) down_trans1(down, downT, lds, bid, t);
}

// Shared frag-read macro for gemm2: tiles linear [rows][128B], XOR2 swizzle.
#define RDA(buf, m4) \
  _Pragma("unroll") for (int mi = 0; mi < 4; ++mi) \
  _Pragma("unroll") for (int kk = 0; kk < 2; ++kk) \
    fa[(m4) + mi][kk] = *(const bf16x8*)((buf) + (ar + ((m4) + mi) * 16) * 128 + ((((kk << 2) | kb) ^ s7a) << 4));

// ===================== GEMM2: 256x256 8-phase, fp32 out =====================
__global__ __launch_bounds__(512, 2) void gemm2_down(const unsigned short* __restrict__ A,
                                                     const unsigned short* __restrict__ BT,
                                                     float* __restrict__ Out) {
  constexpr int MT = C_ / 256;   // 8
  constexpr int NT = H_ / 256;   // 8
  constexpr int NK = I_ / 64;    // 44
  constexpr int NIT = NK / 2;    // 22
  const int nwg = E_ * MT * NT;  // 512
  int bid = blockIdx.x;
  int swz = (bid & 7) * (nwg >> 3) + (bid >> 3);
  int e = swz / (MT * NT);
  int r2 = swz % (MT * NT);
  int m0 = (r2 % MT) << 8;
  int n0 = (r2 / MT) << 8;

  const unsigned short* Ae = A + (size_t)e * C_ * I_ + (size_t)m0 * I_;
  const unsigned short* Be = BT + (size_t)e * H_ * I_ + (size_t)n0 * I_;
  float* Oe = Out + (size_t)e * C_ * H_;

  __shared__ char lds[131072];
  char* const A0b = lds;
  char* const A1b = lds + 32768;
  char* const B0b = lds + 65536;
  char* const B1b = lds + 98304;

  const int t = threadIdx.x, lane = t & 63, w = t >> 6;
  const int wr = (w >> 2) << 7;   // 0 / 128
  const int wc = (w & 3) << 6;    // 0,64,128,192

  const int la = lane & 15, kb = lane >> 4;
  const int ar = wr + la, s7a = ar & 7;
  const int br = wc + la, s7b = br & 7;

  const int sr0 = t >> 3, sc0 = t & 7;
  const int sof0 = sr0 * I_ + ((sc0 ^ (sr0 & 7)) << 3);
  const int sof1 = sof0 + 64 * I_;
  const int dof0 = t << 4, dof1 = (t << 4) + 8192;

#define STG2(gb, ko, lb) do { \
    gload16((gb) + (ko) + sof0, (lb) + dof0); \
    gload16((gb) + (ko) + sof1, (lb) + dof1); } while (0)

#define RDB2(buf, n2) \
  _Pragma("unroll") for (int ni = 0; ni < 2; ++ni) \
  _Pragma("unroll") for (int kk = 0; kk < 2; ++kk) \
    fb[(n2) + ni][kk] = *(const bf16x8*)((buf) + (br + ((n2) + ni) * 16) * 128 + ((((kk << 2) | kb) ^ s7b) << 4));

#define MM4(m4, n2) \
  _Pragma("unroll") for (int mi = 0; mi < 4; ++mi) \
  _Pragma("unroll") for (int ni = 0; ni < 2; ++ni) \
  _Pragma("unroll") for (int kk = 0; kk < 2; ++kk) \
    acc[(m4) + mi][(n2) + ni] = __builtin_amdgcn_mfma_f32_16x16x32_bf16(fa[(m4) + mi][kk], fb[(n2) + ni][kk], acc[(m4) + mi][(n2) + ni], 0, 0, 0);

  f32x4 acc[8][4] = {};
  bf16x8 fa[8][2], fb[4][2];

  // prologue
  STG2(Ae, 0, A0b); STG2(Ae + 128 * I_, 0, A0b + 16384);
  STG2(Be, 0, B0b); STG2(Be + 128 * I_, 0, B0b + 16384);
  STG2(Ae, 64, A1b); STG2(Ae + 128 * I_, 64, A1b + 16384);
  VMC(4); BARX();

#pragma unroll 1
  for (int i = 0; i < NIT; ++i) {
    const int kc = i * 128;
    const bool nx = (i + 1 < NIT);
    // ph1
    RDA(A0b, 0); RDB2(B0b, 0);
    STG2(Be, kc + 64, B1b);
    BARX(); LGKM0();
    PRIO(1); MM4(0, 0); PRIO(0); BARX();
    // ph2
    RDB2(B0b, 2);
    STG2(Be + 128 * I_, kc + 64, B1b + 16384);
    BARX(); LGKM0();
    PRIO(1); MM4(0, 2); PRIO(0); BARX();
    // ph3
    RDA(A0b, 4);
    BARX(); LGKM0();
    PRIO(1); MM4(4, 0); PRIO(0); BARX();
    // ph4
    if (nx) { STG2(Ae, kc + 128, A0b); STG2(Ae + 128 * I_, kc + 128, A0b + 16384); VMC(4); }
    else VMC(0);
    BARX();
    PRIO(1); MM4(4, 2); PRIO(0); BARX();
    // ph5
    RDA(A1b, 0); RDB2(B1b, 0);
    if (nx) STG2(Be, kc + 128, B0b);
    BARX(); LGKM0();
    PRIO(1); MM4(0, 0); PRIO(0); BARX();
    // ph6
    RDB2(B1b, 2);
    if (nx) STG2(Be + 128 * I_, kc + 128, B0b + 16384);
    BARX(); LGKM0();
    PRIO(1); MM4(0, 2); PRIO(0); BARX();
    // ph7
    RDA(A1b, 4);
    BARX(); LGKM0();
    PRIO(1); MM4(4, 0); PRIO(0); BARX();
    // ph8
    if (nx) { STG2(Ae, kc + 192, A1b); STG2(Ae + 128 * I_, kc + 192, A1b + 16384); VMC(4); }
    BARX();
    PRIO(1); MM4(4, 2); PRIO(0); BARX();
  }

  const int rb = m0 + wr + (kb << 2);
  const int cb = n0 + wc + la;
#pragma unroll
  for (int mi = 0; mi < 8; ++mi)
#pragma unroll
    for (int ni = 0; ni < 4; ++ni)
#pragma unroll
      for (int r = 0; r < 4; ++r)
        Oe[(size_t)(rb + mi * 16 + r) * H_ + (cb + ni * 16)] = acc[mi][ni][r];
#undef STG2
}

extern "C" void kernel_launch(void* const* d_in, const int* in_sizes, int n_in,
                              void* d_out, int out_size, void* d_ws, size_t ws_size,
                              hipStream_t stream) {
  const float* hidden = (const float*)d_in[0];
  const float* gateup = (const float*)d_in[1];
  const float* down = (const float*)d_in[2];
  float* out = (float*)d_out;

  unsigned short* ws = (unsigned short*)d_ws;
  unsigned short* hiddenB = ws;                                   // E*C*H bf16
  unsigned short* gateupT = hiddenB + (size_t)E_ * C_ * H_;       // E*2I*H bf16 (transposed)
  unsigned short* downT = gateupT + (size_t)E_ * N1_ * H_;        // E*H*I bf16 (transposed)
  unsigned short* actB = downT + (size_t)E_ * I_ * H_;            // E*C*I bf16

  cvt_bf16<<<2048, 256, 0, stream>>>(hidden, hiddenB, (E_ * C_ * H_) / 8);
  transpose_cvt<<<E_ * (H_ / 256) * (N1_ / 64), 256, 0, stream>>>(gateup, gateupT, H_, N1_);
  gemm1_glu<<<E_ * (C_ / 128) * (I_ / 128), 512, 0, stream>>>(hiddenB, gateupT, actB, down, downT);
  gemm2_down<<<E_ * (C_ / 256) * (H_ / 256), 512, 0, stream>>>(actB, downT, out);
}

// Round 12
// 698.123 us; speedup vs baseline: 1.0812x; 1.0772x over previous
//
#include <hip/hip_runtime.h>
#include <hip/hip_bf16.h>
#include <stdint.h>

// Problem constants (fixed by setup_inputs)
#define E_ 8
#define C_ 2048
#define H_ 2048
#define I_ 2816
#define N1_ (2 * I_)   // 5632

typedef __attribute__((ext_vector_type(8))) short bf16x8;
typedef __attribute__((ext_vector_type(4))) float f32x4;

__device__ __forceinline__ unsigned short f2bf(float f) {
  union { float f; unsigned int u; } v; v.f = f;
  unsigned int u = v.u;
  unsigned int r = (u + 0x7FFFu + ((u >> 16) & 1u)) >> 16;  // RNE
  return (unsigned short)r;
}

__device__ __forceinline__ void gload16(const unsigned short* g, char* l) {
  __builtin_amdgcn_global_load_lds(
      (const __attribute__((address_space(1))) unsigned int*)g,
      (__attribute__((address_space(3))) unsigned int*)l, 16, 0, 0);
}

#define BARX()  do { asm volatile("" ::: "memory"); __builtin_amdgcn_s_barrier(); asm volatile("" ::: "memory"); } while (0)
#define LGKM0() asm volatile("s_waitcnt lgkmcnt(0)" ::: "memory")
#define VMC(n)  asm volatile("s_waitcnt vmcnt(" #n ")" ::: "memory")
#define PRIO(p) __builtin_amdgcn_s_setprio(p)

// ---------------- fp32 -> bf16 straight conversion (vectorized 8/thread) ----
__global__ __launch_bounds__(256) void cvt_bf16(const float* __restrict__ src,
                                                unsigned short* __restrict__ dst,
                                                int n8) {
  int idx = blockIdx.x * 256 + threadIdx.x;
  int stride = gridDim.x * 256;
  for (int i = idx; i < n8; i += stride) {
    const float4* s = (const float4*)(src + (size_t)i * 8);
    float4 a = s[0], b = s[1];
    uint4 o;
    o.x = (unsigned int)f2bf(a.x) | ((unsigned int)f2bf(a.y) << 16);
    o.y = (unsigned int)f2bf(a.z) | ((unsigned int)f2bf(a.w) << 16);
    o.z = (unsigned int)f2bf(b.x) | ((unsigned int)f2bf(b.y) << 16);
    o.w = (unsigned int)f2bf(b.z) | ((unsigned int)f2bf(b.w) << 16);
    *(uint4*)(dst + (size_t)i * 8) = o;
  }
}

// ------- fp32 [R][C] -> bf16 [C][R] per-expert transpose, 64c x 256r tiles --
__global__ __launch_bounds__(256) void transpose_cvt(const float* __restrict__ src,
                                                     unsigned short* __restrict__ dst,
                                                     int R, int C) {
  int tilesC = C >> 6, tilesR = R >> 8;
  int tiles = tilesR * tilesC;
  int bid = blockIdx.x;
  int e = bid / tiles;
  int r2 = bid % tiles;
  int tr = r2 / tilesC, tc = r2 % tilesC;
  const float* s = src + (size_t)e * R * C + (size_t)(tr << 8) * C + (tc << 6);
  unsigned short* d = dst + (size_t)e * R * C + (size_t)(tc << 6) * R + (tr << 8);

  __shared__ unsigned short lds[64 * 256];
  int t = threadIdx.x;
  int tx = t & 15, ty = t >> 4;
  const int g = tx & 7;
#pragma unroll
  for (int p = 0; p < 16; ++p) {
    int row = p * 16 + ty;
    float4 v = *(const float4*)(s + (size_t)row * C + tx * 4);
    int base = tx * 1024 + (((row >> 3) ^ g) << 3) + (row & 7);  // col=4tx
    lds[base]       = f2bf(v.x);
    lds[base + 256] = f2bf(v.y);
    lds[base + 512] = f2bf(v.z);
    lds[base + 768] = f2bf(v.w);
  }
  __syncthreads();
#pragma unroll
  for (int it = 0; it < 8; ++it) {
    int q = it * 256 + t;
    int c = q >> 5, l = q & 31;
    int a = c * 256 + ((l ^ ((c >> 2) & 7)) << 3);
    uint4 vv = *(const uint4*)(&lds[a]);
    *(uint4*)(d + (size_t)c * R + l * 8) = vv;
  }
}

// Embedded down-transpose: 2 tiles (256r x 64c) per gemm1 block (32KB LDS).
__device__ __forceinline__ void down_trans2(const float* __restrict__ down,
                                            unsigned short* __restrict__ downT,
                                            char* ldsbuf, int bid, int t) {
  unsigned short* tl = (unsigned short*)ldsbuf;
  const int tx = t & 15, ty = t >> 4;            // ty 0..31
  const int gx = tx & 7;
#pragma unroll 1
  for (int sub = 0; sub < 2; ++sub) {
    const int T = bid * 2 + sub;                 // 0..2815
    const int te = T / 352;
    const int rr = T % 352;
    const int tr = rr >> 5, tc = rr & 31;
    const float* s = down + (size_t)te * I_ * H_ + (size_t)(tr << 8) * H_ + (tc << 6);
    unsigned short* d = downT + (size_t)te * I_ * H_ + (size_t)(tc << 6) * I_ + (tr << 8);
    __syncthreads();
#pragma unroll
    for (int p = 0; p < 8; ++p) {
      int row = p * 32 + ty;
      float4 v = *(const float4*)(s + (size_t)row * H_ + tx * 4);
      int base = tx * 1024 + (((row >> 3) ^ gx) << 3) + (row & 7);
      tl[base]       = f2bf(v.x);
      tl[base + 256] = f2bf(v.y);
      tl[base + 512] = f2bf(v.z);
      tl[base + 768] = f2bf(v.w);
    }
    __syncthreads();
#pragma unroll
    for (int it = 0; it < 4; ++it) {
      int q = it * 512 + t;
      int c = q >> 5, l = q & 31;
      int a = c * 256 + ((l ^ ((c >> 2) & 7)) << 3);
      uint4 vv = *(const uint4*)(&tl[a]);
      *(uint4*)(d + (size_t)c * I_ + l * 8) = vv;
    }
  }
  __syncthreads();
}

// Shared frag-read macro: A/B tiles linear [rows][128B], XOR2 chunk swizzle.
#define RDA(buf, m4) \
  _Pragma("unroll") for (int mi = 0; mi < 4; ++mi) \
  _Pragma("unroll") for (int kk = 0; kk < 2; ++kk) \
    fa[(m4) + mi][kk] = *(const bf16x8*)((buf) + (ar + ((m4) + mi) * 16) * 128 + ((((kk << 2) | kb) ^ s7a) << 4));

// ===================== GEMM1: 256x128 dual-B 8-phase GLU ====================
// Embedded down-transpose parity-split: even bid -> before K-loop, odd -> after.
__global__ __launch_bounds__(512, 2) void gemm1_glu(const unsigned short* __restrict__ A,
                                                    const unsigned short* __restrict__ BT,
                                                    unsigned short* __restrict__ act,
                                                    const float* __restrict__ down,
                                                    unsigned short* __restrict__ downT) {
  constexpr int MT = C_ / 256;   // 8
  constexpr int NT = I_ / 128;   // 22
  constexpr int NK = H_ / 64;    // 32
  constexpr int NIT = NK / 2;    // 16
  const int nwg = E_ * MT * NT;  // 1408
  int bid = blockIdx.x;
  int swz = (bid & 7) * (nwg >> 3) + (bid >> 3);
  int e = swz / (MT * NT);
  int r2 = swz % (MT * NT);
  int m0 = (r2 % MT) << 8;
  int n0 = (r2 / MT) << 7;

  const unsigned short* Ae = A + (size_t)e * C_ * H_ + (size_t)m0 * H_;
  const unsigned short* Ge = BT + (size_t)e * N1_ * H_ + (size_t)n0 * H_;
  const unsigned short* Ue = Ge + (size_t)I_ * H_;
  unsigned short* Ce = act + (size_t)e * C_ * I_;

  __shared__ char lds[131072];
  char* const A0b = lds;
  char* const A1b = lds + 32768;
  char* const B0b = lds + 65536;
  char* const B1b = lds + 98304;

  const int t = threadIdx.x, lane = t & 63, w = t >> 6;
  const int wr = (w >> 2) << 7;   // 0 / 128
  const int wc = (w & 3) << 5;    // 0,32,64,96

  const int la = lane & 15, kb = lane >> 4;
  const int ar = wr + la, s7a = ar & 7;
  const int br = wc + la, s7b = br & 7;

  const int sr0 = t >> 3, sc0 = t & 7;
  const int sof0 = sr0 * H_ + ((sc0 ^ (sr0 & 7)) << 3);
  const int sof1 = sof0 + 64 * H_;
  const int dof0 = t << 4, dof1 = (t << 4) + 8192;

  // even blocks: stream the down-transpose first (overlaps odd blocks' MFMA)
  if ((bid & 1) == 0) down_trans2(down, downT, lds, bid, t);

#define STG1(gb, ko, lb) do { \
    gload16((gb) + (ko) + sof0, (lb) + dof0); \
    gload16((gb) + (ko) + sof1, (lb) + dof1); } while (0)

#define RDBG(buf, dst, ro) \
  _Pragma("unroll") for (int ni = 0; ni < 2; ++ni) \
  _Pragma("unroll") for (int kk = 0; kk < 2; ++kk) \
    dst[ni][kk] = *(const bf16x8*)((buf) + ((ro) + br + ni * 16) * 128 + ((((kk << 2) | kb) ^ s7b) << 4));

#define MMG(accA, m4, bfr) \
  _Pragma("unroll") for (int mi = 0; mi < 4; ++mi) \
  _Pragma("unroll") for (int ni = 0; ni < 2; ++ni) \
  _Pragma("unroll") for (int kk = 0; kk < 2; ++kk) \
    accA[(m4) + mi][ni] = __builtin_amdgcn_mfma_f32_16x16x32_bf16(fa[(m4) + mi][kk], bfr[ni][kk], accA[(m4) + mi][ni], 0, 0, 0);

  f32x4 accg[8][2] = {};
  f32x4 accu[8][2] = {};
  bf16x8 fa[8][2], fg[2][2], fu[2][2];

  // prologue: tile0 {Ah0,Ah1,Bg,Bu}, tile1 {Ah0,Ah1}
  STG1(Ae, 0, A0b); STG1(Ae + 128 * H_, 0, A0b + 16384);
  STG1(Ge, 0, B0b); STG1(Ue, 0, B0b + 16384);
  STG1(Ae, 64, A1b); STG1(Ae + 128 * H_, 64, A1b + 16384);
  VMC(4); BARX();

#pragma unroll 1
  for (int i = 0; i < NIT; ++i) {
    const int kc = i * 128;
    const bool nx = (i + 1 < NIT);
    // ph1: read a(mh0)+bg from buf0; stage (T+1).Bg -> B1
    RDA(A0b, 0); RDBG(B0b, fg, 0);
    STG1(Ge, kc + 64, B1b);
    BARX(); LGKM0();
    PRIO(1); MMG(accg, 0, fg); PRIO(0); BARX();
    // ph2: read bu; stage (T+1).Bu -> B1
    RDBG(B0b, fu, 128);
    STG1(Ue, kc + 64, B1b + 16384);
    BARX(); LGKM0();
    PRIO(1); MMG(accu, 0, fu); PRIO(0); BARX();
    // ph3: read a(mh1)
    RDA(A0b, 4);
    BARX(); LGKM0();
    PRIO(1); MMG(accg, 4, fg); PRIO(0); BARX();
    // ph4: stage (T+2).A (both halves) -> A0; vmcnt keeps 4 in flight
    if (nx) { STG1(Ae, kc + 128, A0b); STG1(Ae + 128 * H_, kc + 128, A0b + 16384); VMC(4); }
    else VMC(0);
    BARX();
    PRIO(1); MMG(accu, 4, fu); PRIO(0); BARX();
    // ph5: read buf1 a(mh0)+bg; stage (T+2).Bg -> B0
    RDA(A1b, 0); RDBG(B1b, fg, 0);
    if (nx) STG1(Ge, kc + 128, B0b);
    BARX(); LGKM0();
    PRIO(1); MMG(accg, 0, fg); PRIO(0); BARX();
    // ph6: read buf1 bu; stage (T+2).Bu -> B0
    RDBG(B1b, fu, 128);
    if (nx) STG1(Ue, kc + 128, B0b + 16384);
    BARX(); LGKM0();
    PRIO(1); MMG(accu, 0, fu); PRIO(0); BARX();
    // ph7: read buf1 a(mh1)
    RDA(A1b, 4);
    BARX(); LGKM0();
    PRIO(1); MMG(accg, 4, fg); PRIO(0); BARX();
    // ph8: stage (T+3).A (both halves) -> A1
    if (nx) { STG1(Ae, kc + 192, A1b); STG1(Ae + 128 * H_, kc + 192, A1b + 16384); VMC(4); }
    BARX();
    PRIO(1); MMG(accu, 4, fu); PRIO(0); BARX();
  }

  // Epilogue: act = silu(g) * u. C/D layout: col=lane&15, row=(lane>>4)*4+reg
  const int rb = m0 + wr + (kb << 2);
  const int cb = n0 + wc + la;
#pragma unroll
  for (int mi = 0; mi < 8; ++mi)
#pragma unroll
    for (int ni = 0; ni < 2; ++ni)
#pragma unroll
      for (int r = 0; r < 4; ++r) {
        float g = accg[mi][ni][r], u = accu[mi][ni][r];
        float s = g / (1.0f + __expf(-g));
        Ce[(size_t)(rb + mi * 16 + r) * I_ + (cb + ni * 16)] = f2bf(s * u);
      }

  // odd blocks: stream the down-transpose last (overlaps even blocks' MFMA)
  if (bid & 1) down_trans2(down, downT, lds, bid, t);
#undef STG1
}

// ===================== GEMM2: 256x256 8-phase, fp32 out =====================
// A: [E][C][I] bf16. BT: [E][H][I] bf16 (n-major). Out: [E][C][H] fp32.
__global__ __launch_bounds__(512, 2) void gemm2_down(const unsigned short* __restrict__ A,
                                                     const unsigned short* __restrict__ BT,
                                                     float* __restrict__ Out) {
  constexpr int MT = C_ / 256;   // 8
  constexpr int NT = H_ / 256;   // 8
  constexpr int NK = I_ / 64;    // 44
  constexpr int NIT = NK / 2;    // 22
  const int nwg = E_ * MT * NT;  // 512
  int bid = blockIdx.x;
  int swz = (bid & 7) * (nwg >> 3) + (bid >> 3);
  int e = swz / (MT * NT);
  int r2 = swz % (MT * NT);
  int m0 = (r2 % MT) << 8;
  int n0 = (r2 / MT) << 8;

  const unsigned short* Ae = A + (size_t)e * C_ * I_ + (size_t)m0 * I_;
  const unsigned short* Be = BT + (size_t)e * H_ * I_ + (size_t)n0 * I_;
  float* Oe = Out + (size_t)e * C_ * H_;

  __shared__ char lds[131072];
  char* const A0b = lds;
  char* const A1b = lds + 32768;
  char* const B0b = lds + 65536;
  char* const B1b = lds + 98304;

  const int t = threadIdx.x, lane = t & 63, w = t >> 6;
  const int wr = (w >> 2) << 7;   // 0 / 128
  const int wc = (w & 3) << 6;    // 0,64,128,192

  const int la = lane & 15, kb = lane >> 4;
  const int ar = wr + la, s7a = ar & 7;
  const int br = wc + la, s7b = br & 7;

  const int sr0 = t >> 3, sc0 = t & 7;
  const int sof0 = sr0 * I_ + ((sc0 ^ (sr0 & 7)) << 3);
  const int sof1 = sof0 + 64 * I_;
  const int dof0 = t << 4, dof1 = (t << 4) + 8192;

#define STG2(gb, ko, lb) do { \
    gload16((gb) + (ko) + sof0, (lb) + dof0); \
    gload16((gb) + (ko) + sof1, (lb) + dof1); } while (0)

#define RDB2(buf, n2) \
  _Pragma("unroll") for (int ni = 0; ni < 2; ++ni) \
  _Pragma("unroll") for (int kk = 0; kk < 2; ++kk) \
    fb[(n2) + ni][kk] = *(const bf16x8*)((buf) + (br + ((n2) + ni) * 16) * 128 + ((((kk << 2) | kb) ^ s7b) << 4));

#define MM4(m4, n2) \
  _Pragma("unroll") for (int mi = 0; mi < 4; ++mi) \
  _Pragma("unroll") for (int ni = 0; ni < 2; ++ni) \
  _Pragma("unroll") for (int kk = 0; kk < 2; ++kk) \
    acc[(m4) + mi][(n2) + ni] = __builtin_amdgcn_mfma_f32_16x16x32_bf16(fa[(m4) + mi][kk], fb[(n2) + ni][kk], acc[(m4) + mi][(n2) + ni], 0, 0, 0);

  f32x4 acc[8][4] = {};
  bf16x8 fa[8][2], fb[4][2];

  // prologue
  STG2(Ae, 0, A0b); STG2(Ae + 128 * I_, 0, A0b + 16384);
  STG2(Be, 0, B0b); STG2(Be + 128 * I_, 0, B0b + 16384);
  STG2(Ae, 64, A1b); STG2(Ae + 128 * I_, 64, A1b + 16384);
  VMC(4); BARX();

#pragma unroll 1
  for (int i = 0; i < NIT; ++i) {
    const int kc = i * 128;
    const bool nx = (i + 1 < NIT);
    // ph1
    RDA(A0b, 0); RDB2(B0b, 0);
    STG2(Be, kc + 64, B1b);
    BARX(); LGKM0();
    PRIO(1); MM4(0, 0); PRIO(0); BARX();
    // ph2
    RDB2(B0b, 2);
    STG2(Be + 128 * I_, kc + 64, B1b + 16384);
    BARX(); LGKM0();
    PRIO(1); MM4(0, 2); PRIO(0); BARX();
    // ph3
    RDA(A0b, 4);
    BARX(); LGKM0();
    PRIO(1); MM4(4, 0); PRIO(0); BARX();
    // ph4
    if (nx) { STG2(Ae, kc + 128, A0b); STG2(Ae + 128 * I_, kc + 128, A0b + 16384); VMC(4); }
    else VMC(0);
    BARX();
    PRIO(1); MM4(4, 2); PRIO(0); BARX();
    // ph5
    RDA(A1b, 0); RDB2(B1b, 0);
    if (nx) STG2(Be, kc + 128, B0b);
    BARX(); LGKM0();
    PRIO(1); MM4(0, 0); PRIO(0); BARX();
    // ph6
    RDB2(B1b, 2);
    if (nx) STG2(Be + 128 * I_, kc + 128, B0b + 16384);
    BARX(); LGKM0();
    PRIO(1); MM4(0, 2); PRIO(0); BARX();
    // ph7
    RDA(A1b, 4);
    BARX(); LGKM0();
    PRIO(1); MM4(4, 0); PRIO(0); BARX();
    // ph8
    if (nx) { STG2(Ae, kc + 192, A1b); STG2(Ae + 128 * I_, kc + 192, A1b + 16384); VMC(4); }
    BARX();
    PRIO(1); MM4(4, 2); PRIO(0); BARX();
  }

  const int rb = m0 + wr + (kb << 2);
  const int cb = n0 + wc + la;
#pragma unroll
  for (int mi = 0; mi < 8; ++mi)
#pragma unroll
    for (int ni = 0; ni < 4; ++ni)
#pragma unroll
      for (int r = 0; r < 4; ++r)
        Oe[(size_t)(rb + mi * 16 + r) * H_ + (cb + ni * 16)] = acc[mi][ni][r];
#undef STG2
}

extern "C" void kernel_launch(void* const* d_in, const int* in_sizes, int n_in,
                              void* d_out, int out_size, void* d_ws, size_t ws_size,
                              hipStream_t stream) {
  const float* hidden = (const float*)d_in[0];
  const float* gateup = (const float*)d_in[1];
  const float* down = (const float*)d_in[2];
  float* out = (float*)d_out;

  unsigned short* ws = (unsigned short*)d_ws;
  unsigned short* hiddenB = ws;                                   // E*C*H bf16
  unsigned short* gateupT = hiddenB + (size_t)E_ * C_ * H_;       // E*2I*H bf16 (transposed)
  unsigned short* downT = gateupT + (size_t)E_ * N1_ * H_;        // E*H*I bf16 (transposed)
  unsigned short* actB = downT + (size_t)E_ * I_ * H_;            // E*C*I bf16

  cvt_bf16<<<2048, 256, 0, stream>>>(hidden, hiddenB, (E_ * C_ * H_) / 8);
  transpose_cvt<<<E_ * (H_ / 256) * (N1_ / 64), 256, 0, stream>>>(gateup, gateupT, H_, N1_);
  gemm1_glu<<<E_ * (C_ / 256) * (I_ / 128), 512, 0, stream>>>(hiddenB, gateupT, actB, down, downT);
  gemm2_down<<<E_ * (C_ / 256) * (H_ / 256), 512, 0, stream>>>(actB, downT, out);
}